// Round 17
// baseline (232.614 us; speedup 1.0000x reference)
//
#include <hip/hip_runtime.h>
#include <hip/hip_bf16.h>

#define IN_C 128
#define HEADS 12
#define OUT_C 32
#define HC 384   // HEADS*OUT_C
#define BK 96    // bucket capacity per dst (P(deg>=96), lambda=16: ~1e-48)
#define NEG_SLOPE 0.2f
#define LOG2E 1.44269504f

typedef __attribute__((ext_vector_type(8))) short bf16x8;
typedef __attribute__((ext_vector_type(4))) float f32x4;

static __device__ __forceinline__ unsigned short bfbits(float f) {
    __hip_bfloat16 b = __float2bfloat16(f);
    return *reinterpret_cast<unsigned short*>(&b);
}
static __device__ __forceinline__ float bflo(unsigned int g) {
    return __uint_as_float(g << 16);
}
static __device__ __forceinline__ float bfhi(unsigned int g) {
    return __uint_as_float(g & 0xffff0000u);
}

// ---------------- kernel 0: prep — transpose W -> Wt bf16 [384][128], zero cursor ----------------
__global__ void k_prep(const float* __restrict__ W, __hip_bfloat16* __restrict__ Wt,
                       int* __restrict__ cursor, int N) {
    int i = blockIdx.x * 256 + threadIdx.x;
    if (i < IN_C * HC) {
        int k = i & 127, col = i >> 7;
        Wt[i] = __float2bfloat16(W[k * HC + col]);
    } else if (i - IN_C * HC < N) {
        cursor[i - IN_C * HC] = 0;
    }
}

// ---------------- kernel 1 (fused): MFMA gemm+att  |  edge bucket scatter ----------------
// blocks [0, GB): gemm. 4 waves x 16 rows = 64-row tile; A from LDS x-tile (1 sync),
// B-frags straight from global Wt (L2-resident, no LDS staging, no per-head syncs).
// blocks [GB, ...): scatter edges into per-dst buckets (independent of gemm output).
__global__ __launch_bounds__(256) void k_gemm_scatter(
    const float* __restrict__ x, const __hip_bfloat16* __restrict__ Wt,
    const float* __restrict__ att_src, const float* __restrict__ att_dst,
    __hip_bfloat16* __restrict__ h2out, float* __restrict__ a_src,
    float* __restrict__ a_dst, const int* __restrict__ ei,
    int* __restrict__ cursor, int* __restrict__ csr_src,
    int N, int E, int GB) {
    if (blockIdx.x >= GB) {  // ---- scatter part ----
        int e = (blockIdx.x - GB) * 256 + threadIdx.x;
        if (e < E) {
            int s = ei[e];       // plane 0 = src
            int d = ei[E + e];   // plane 1 = dst
            int pos = atomicAdd(&cursor[d], 1);
            if (pos < BK) csr_src[d * BK + pos] = s;
        }
        return;
    }
    // ---- gemm part ----
    __shared__ unsigned short xs[64 * 136];  // 17408 B (bf16 x-tile, padded)
    const int tid = threadIdx.x;
    const int row0 = blockIdx.x * 64;
    for (int i = tid * 4; i < 64 * IN_C; i += 1024) {
        int r = i >> 7, k = i & 127;
        float4 v = make_float4(0.f, 0.f, 0.f, 0.f);
        if (row0 + r < N) v = *reinterpret_cast<const float4*>(x + (size_t)(row0 + r) * IN_C + k);
        unsigned short* dst = xs + r * 136 + k;
        dst[0] = bfbits(v.x); dst[1] = bfbits(v.y); dst[2] = bfbits(v.z); dst[3] = bfbits(v.w);
    }
    __syncthreads();
    const int l = tid & 63;
    const int wrow = (tid >> 6) * 16;  // wave's 16-row slice
    const int lr = l & 15;             // A-row / B-col / D-col
    const int ks = l >> 4;             // k-octet group
    bf16x8 afr[4];                     // A-frags: constant across heads
#pragma unroll
    for (int t = 0; t < 4; ++t)
        afr[t] = *reinterpret_cast<const bf16x8*>(xs + (wrow + lr) * 136 + t * 32 + ks * 8);
    // per-lane B base: Wt[col=lr][k-octet ks]
    const unsigned short* wb = reinterpret_cast<const unsigned short*>(Wt) + lr * IN_C + ks * 8;

    for (int h = 0; h < HEADS; ++h) {
        const unsigned short* wh = wb + h * 32 * IN_C;
        f32x4 acc0 = {0.f, 0.f, 0.f, 0.f}, acc1 = {0.f, 0.f, 0.f, 0.f};
#pragma unroll
        for (int t = 0; t < 4; ++t) {
            bf16x8 b0 = *reinterpret_cast<const bf16x8*>(wh + t * 32);
            bf16x8 b1 = *reinterpret_cast<const bf16x8*>(wh + 16 * IN_C + t * 32);
            acc0 = __builtin_amdgcn_mfma_f32_16x16x32_bf16(afr[t], b0, acc0, 0, 0, 0);
            acc1 = __builtin_amdgcn_mfma_f32_16x16x32_bf16(afr[t], b1, acc1, 0, 0, 0);
        }
        // epilogue: h2 store + att partial dots (D layout: col=lane&15, row=(lane>>4)*4+reg)
        const float as0 = att_src[h * 32 + lr], as1 = att_src[h * 32 + 16 + lr];
        const float ad0 = att_dst[h * 32 + lr], ad1 = att_dst[h * 32 + 16 + lr];
        float ps[4], pd[4];
#pragma unroll
        for (int r = 0; r < 4; ++r) {
            int grow = row0 + wrow + ks * 4 + r;
            ps[r] = acc0[r] * as0 + acc1[r] * as1;
            pd[r] = acc0[r] * ad0 + acc1[r] * ad1;
            if (grow < N) {
                h2out[(size_t)grow * HC + h * 32 + lr] = __float2bfloat16(acc0[r]);
                h2out[(size_t)grow * HC + h * 32 + 16 + lr] = __float2bfloat16(acc1[r]);
            }
        }
#pragma unroll
        for (int off = 1; off <= 8; off <<= 1) {
#pragma unroll
            for (int r = 0; r < 4; ++r) {
                ps[r] += __shfl_xor(ps[r], off);
                pd[r] += __shfl_xor(pd[r], off);
            }
        }
        if (lr == 0) {
#pragma unroll
            for (int r = 0; r < 4; ++r) {
                int grow = row0 + wrow + ks * 4 + r;
                if (grow < N) {
                    a_src[grow * HEADS + h] = ps[r] * LOG2E;  // pre-scaled for exp2
                    a_dst[grow * HEADS + h] = pd[r] * LOG2E;
                }
            }
        }
    }
}

// ---------------- aggregation: one wave per dst, 4-edge unroll, exp2 ----------------
// Pinned by gather-path bandwidth (653 MB random row-gathers ~6.4 TB/s effective).
__global__ __launch_bounds__(256) void k_aggregate(
    const int* __restrict__ cursor, const int* __restrict__ csr_src,
    const unsigned int* __restrict__ h2u, const float* __restrict__ a_src,
    const float* __restrict__ a_dst, const float* __restrict__ bias,
    float* __restrict__ y, int N) {
    const int d = (blockIdx.x * 256 + threadIdx.x) >> 6;  // wave id = dst node
    if (d >= N) return;
    const int l = threadIdx.x & 63;
    const int h0 = l >> 4;
    const float adv0 = a_dst[d * HEADS + h0];
    const float adv1 = a_dst[d * HEADS + h0 + 4];
    const float adv2 = a_dst[d * HEADS + h0 + 8];
    float ax0 = 0.f, ay0 = 0.f, ax1 = 0.f, ay1 = 0.f, ax2 = 0.f, ay2 = 0.f;
    float den0 = 0.f, den1 = 0.f, den2 = 0.f;
    const int m = min(cursor[d], BK);
    const int* bucket = csr_src + d * BK;
    int j = 0;
    for (; j + 4 <= m; j += 4) {
        int4 ss = *reinterpret_cast<const int4*>(bucket + j);
        int sa[4] = {ss.x, ss.y, ss.z, ss.w};
#pragma unroll
        for (int q = 0; q < 4; ++q) {
            const float* ap = a_src + sa[q] * HEADS;
            unsigned r = (unsigned)sa[q] * 192u;
            unsigned g0 = h2u[r + l], g1 = h2u[r + l + 64], g2 = h2u[r + l + 128];
            float v0 = ap[h0] + adv0;
            float v1 = ap[h0 + 4] + adv1;
            float v2 = ap[h0 + 8] + adv2;
            v0 = fmaxf(v0, NEG_SLOPE * v0);
            v1 = fmaxf(v1, NEG_SLOPE * v1);
            v2 = fmaxf(v2, NEG_SLOPE * v2);
            float w0 = exp2f(v0), w1 = exp2f(v1), w2 = exp2f(v2);
            ax0 = fmaf(w0, bflo(g0), ax0); ay0 = fmaf(w0, bfhi(g0), ay0); den0 += w0;
            ax1 = fmaf(w1, bflo(g1), ax1); ay1 = fmaf(w1, bfhi(g1), ay1); den1 += w1;
            ax2 = fmaf(w2, bflo(g2), ax2); ay2 = fmaf(w2, bfhi(g2), ay2); den2 += w2;
        }
    }
    for (; j < m; ++j) {
        int s = bucket[j];
        const float* ap = a_src + s * HEADS;
        unsigned r = (unsigned)s * 192u;
        unsigned g0 = h2u[r + l], g1 = h2u[r + l + 64], g2 = h2u[r + l + 128];
        float v0 = ap[h0] + adv0;
        float v1 = ap[h0 + 4] + adv1;
        float v2 = ap[h0 + 8] + adv2;
        v0 = fmaxf(v0, NEG_SLOPE * v0);
        v1 = fmaxf(v1, NEG_SLOPE * v1);
        v2 = fmaxf(v2, NEG_SLOPE * v2);
        float w0 = exp2f(v0), w1 = exp2f(v1), w2 = exp2f(v2);
        ax0 = fmaf(w0, bflo(g0), ax0); ay0 = fmaf(w0, bfhi(g0), ay0); den0 += w0;
        ax1 = fmaf(w1, bflo(g1), ax1); ay1 = fmaf(w1, bfhi(g1), ay1); den1 += w1;
        ax2 = fmaf(w2, bflo(g2), ax2); ay2 = fmaf(w2, bfhi(g2), ay2); den2 += w2;
    }
    {  // self-loop (s == d)
        const float* ap = a_src + d * HEADS;
        unsigned r = (unsigned)d * 192u;
        unsigned g0 = h2u[r + l], g1 = h2u[r + l + 64], g2 = h2u[r + l + 128];
        float v0 = ap[h0] + adv0;
        float v1 = ap[h0 + 4] + adv1;
        float v2 = ap[h0 + 8] + adv2;
        v0 = fmaxf(v0, NEG_SLOPE * v0);
        v1 = fmaxf(v1, NEG_SLOPE * v1);
        v2 = fmaxf(v2, NEG_SLOPE * v2);
        float w0 = exp2f(v0), w1 = exp2f(v1), w2 = exp2f(v2);
        ax0 = fmaf(w0, bflo(g0), ax0); ay0 = fmaf(w0, bfhi(g0), ay0); den0 += w0;
        ax1 = fmaf(w1, bflo(g1), ax1); ay1 = fmaf(w1, bfhi(g1), ay1); den1 += w1;
        ax2 = fmaf(w2, bflo(g2), ax2); ay2 = fmaf(w2, bfhi(g2), ay2); den2 += w2;
    }
    float tx = ax0 / (den0 + 1e-16f) + ax1 / (den1 + 1e-16f) + ax2 / (den2 + 1e-16f);
    float ty = ay0 / (den0 + 1e-16f) + ay1 / (den1 + 1e-16f) + ay2 / (den2 + 1e-16f);
    tx += __shfl_xor(tx, 16); ty += __shfl_xor(ty, 16);
    tx += __shfl_xor(tx, 32); ty += __shfl_xor(ty, 32);
    if (l < 16) {
        float2 b = *reinterpret_cast<const float2*>(bias + 2 * l);
        float2 o;
        o.x = fmaxf(tx * (1.f / HEADS) + b.x, 0.f);
        o.y = fmaxf(ty * (1.f / HEADS) + b.y, 0.f);
        *reinterpret_cast<float2*>(y + (size_t)d * OUT_C + 2 * l) = o;
    }
}

// ---------------- MLP epilogue ----------------
__global__ __launch_bounds__(256) void k_mlp(const float* __restrict__ y_in,
                                             const float* __restrict__ W1,
                                             const float* __restrict__ b1,
                                             const float* __restrict__ W2,
                                             const float* __restrict__ b2,
                                             float* __restrict__ out, int N) {
    __shared__ float sW1[OUT_C * 64];
    __shared__ float sW2[64 * OUT_C];
    __shared__ float sb1[64];
    __shared__ float sb2[OUT_C];
    const int tid = threadIdx.x;
    for (int i = tid; i < OUT_C * 64; i += 256) { sW1[i] = W1[i]; sW2[i] = W2[i]; }
    if (tid < 64) sb1[tid] = b1[tid];
    if (tid < OUT_C) sb2[tid] = b2[tid];
    __syncthreads();
    const int n = blockIdx.x * 256 + tid;
    if (n >= N) return;
    float y[OUT_C];
#pragma unroll
    for (int c = 0; c < OUT_C / 4; ++c) {
        float4 v = *reinterpret_cast<const float4*>(y_in + (size_t)n * OUT_C + 4 * c);
        y[4 * c + 0] = v.x; y[4 * c + 1] = v.y; y[4 * c + 2] = v.z; y[4 * c + 3] = v.w;
    }
    float z2[OUT_C];
#pragma unroll
    for (int c = 0; c < OUT_C; ++c) z2[c] = sb2[c];
    for (int j = 0; j < 64; ++j) {
        float t = sb1[j];
#pragma unroll
        for (int c = 0; c < OUT_C; ++c) t = fmaf(y[c], sW1[c * 64 + j], t);
        t = t > 0.f ? t : 0.f;
#pragma unroll
        for (int c = 0; c < OUT_C; ++c) z2[c] = fmaf(t, sW2[j * OUT_C + c], z2[c]);
    }
#pragma unroll
    for (int c = 0; c < OUT_C; ++c) {
        float r = y[c] + z2[c];
        r = r > 0.f ? r : 0.f;
        out[(size_t)n * OUT_C + c] = r;
    }
}

extern "C" void kernel_launch(void* const* d_in, const int* in_sizes, int n_in,
                              void* d_out, int out_size, void* d_ws, size_t ws_size,
                              hipStream_t stream) {
    const float* x = (const float*)d_in[0];
    const int* ei = (const int*)d_in[1];  // int32 planar [2,E]
    const float* W = (const float*)d_in[2];
    const float* att_src = (const float*)d_in[3];
    const float* att_dst = (const float*)d_in[4];
    const float* bias = (const float*)d_in[5];
    const float* W1 = (const float*)d_in[6];
    const float* b1 = (const float*)d_in[7];
    const float* W2 = (const float*)d_in[8];
    const float* b2 = (const float*)d_in[9];
    const int N = in_sizes[0] / IN_C;
    const int E = in_sizes[1] / 2;

    // workspace: h2[N*384]bf16 | a_src[N*12]f32 | a_dst[N*12] | y[N*32] |
    //            cursor[N]i32 | csr_src[N*BK]i32 | Wt[128*384]bf16
    char* ws = (char*)d_ws;
    __hip_bfloat16* h2 = (__hip_bfloat16*)ws;
    float* a_src = (float*)(ws + (size_t)N * HC * 2);
    float* a_dst = a_src + (size_t)N * HEADS;
    float* y = a_dst + (size_t)N * HEADS;
    int* cursor = (int*)(y + (size_t)N * OUT_C);
    int* csr_src = cursor + N;
    __hip_bfloat16* Wt = (__hip_bfloat16*)(csr_src + (size_t)N * BK);

    int prep_blocks = (IN_C * HC + N + 255) / 256;
    k_prep<<<prep_blocks, 256, 0, stream>>>(W, Wt, cursor, N);

    int GB = (N + 63) / 64;
    int SB = (E + 255) / 256;
    k_gemm_scatter<<<GB + SB, 256, 0, stream>>>(x, Wt, att_src, att_dst, h2,
                                                a_src, a_dst, ei, cursor, csr_src,
                                                N, E, GB);

    int agg_blocks = (N * 64 + 255) / 256;  // one wave per dst
    k_aggregate<<<agg_blocks, 256, 0, stream>>>(cursor, csr_src,
                                                (const unsigned int*)h2, a_src, a_dst,
                                                bias, y, N);
    k_mlp<<<(N + 255) / 256, 256, 0, stream>>>(y, W1, b1, W2, b2, (float*)d_out, N);
}

// Round 18
// 230.380 us; speedup vs baseline: 1.0097x; 1.0097x over previous
//
#include <hip/hip_runtime.h>
#include <hip/hip_bf16.h>

#define IN_C 128
#define HEADS 12
#define OUT_C 32
#define HC 384   // HEADS*OUT_C
#define BK 96    // bucket capacity per dst (P(deg>=96), lambda=16: ~1e-48)
#define NEG_SLOPE 0.2f
#define LOG2E 1.44269504f
#define AUGC 416  // 384 h-cols + 16 (12 Wa + pad) + 16 (12 Wd + pad)

typedef __attribute__((ext_vector_type(8))) short bf16x8;
typedef __attribute__((ext_vector_type(4))) float f32x4;

static __device__ __forceinline__ unsigned short bfbits(float f) {
    __hip_bfloat16 b = __float2bfloat16(f);
    return *reinterpret_cast<unsigned short*>(&b);
}
static __device__ __forceinline__ float bflo(unsigned int g) {
    return __uint_as_float(g << 16);
}
static __device__ __forceinline__ float bfhi(unsigned int g) {
    return __uint_as_float(g & 0xffff0000u);
}

// ---------------- kernel 0: prep ----------------
// Waug[col][k] bf16: cols 0..383 = W^T; cols 384+h = LOG2E * (W-head-h @ att_src_h);
// cols 400+h = LOG2E * (W-head-h @ att_dst_h); pad cols zero. Also zeroes cursor.
__global__ void k_prep(const float* __restrict__ W, const float* __restrict__ att_src,
                       const float* __restrict__ att_dst,
                       __hip_bfloat16* __restrict__ Waug, int* __restrict__ cursor,
                       int N) {
    int i = blockIdx.x * 256 + threadIdx.x;
    if (i < HC * IN_C) {
        int col = i >> 7, k = i & 127;
        Waug[(size_t)col * IN_C + k] = __float2bfloat16(W[k * HC + col]);
    } else if (i < AUGC * IN_C) {
        int j = i - HC * IN_C;
        int idx = j >> 7;  // 0..31 (aug col index)
        int k = j & 127;
        float v = 0.f;
        if (idx < HEADS) {  // Wa
            for (int c = 0; c < 32; ++c) v += W[k * HC + idx * 32 + c] * att_src[idx * 32 + c];
            v *= LOG2E;
        } else if (idx >= 16 && idx < 16 + HEADS) {  // Wd
            int h = idx - 16;
            for (int c = 0; c < 32; ++c) v += W[k * HC + h * 32 + c] * att_dst[h * 32 + c];
            v *= LOG2E;
        }
        Waug[(size_t)(HC + idx) * IN_C + k] = __float2bfloat16(v);
    } else if (i - AUGC * IN_C < N) {
        cursor[i - AUGC * IN_C] = 0;
    }
}

// ---------------- kernel 1 (fused): MFMA gemm (h2 + a_src/a_dst)  |  edge scatter ----------------
// gemm blocks: 4 waves x 16 rows; A from LDS x-tile (1 sync); B straight from global
// Waug (L2-resident). a_src/a_dst are just 2 more MFMA column-blocks -> direct stores,
// no shuffle reductions.
__global__ __launch_bounds__(256) void k_gemm_scatter(
    const float* __restrict__ x, const __hip_bfloat16* __restrict__ Waug,
    __hip_bfloat16* __restrict__ h2out, float* __restrict__ a_src,
    float* __restrict__ a_dst, const int* __restrict__ ei,
    int* __restrict__ cursor, int* __restrict__ csr_src,
    int N, int E, int GB) {
    if (blockIdx.x >= GB) {  // ---- scatter part ----
        int e = (blockIdx.x - GB) * 256 + threadIdx.x;
        if (e < E) {
            int s = ei[e];       // plane 0 = src
            int d = ei[E + e];   // plane 1 = dst
            int pos = atomicAdd(&cursor[d], 1);
            if (pos < BK) csr_src[d * BK + pos] = s;
        }
        return;
    }
    // ---- gemm part ----
    __shared__ unsigned short xs[64 * 136];  // bf16 x-tile, padded
    const int tid = threadIdx.x;
    const int row0 = blockIdx.x * 64;
    for (int i = tid * 4; i < 64 * IN_C; i += 1024) {
        int r = i >> 7, k = i & 127;
        float4 v = make_float4(0.f, 0.f, 0.f, 0.f);
        if (row0 + r < N) v = *reinterpret_cast<const float4*>(x + (size_t)(row0 + r) * IN_C + k);
        unsigned short* dst = xs + r * 136 + k;
        dst[0] = bfbits(v.x); dst[1] = bfbits(v.y); dst[2] = bfbits(v.z); dst[3] = bfbits(v.w);
    }
    __syncthreads();
    const int l = tid & 63;
    const int wrow = (tid >> 6) * 16;  // wave's 16-row slice
    const int lr = l & 15;             // A-row / B-col / D-col
    const int ks = l >> 4;             // k-octet group
    bf16x8 afr[4];
#pragma unroll
    for (int t = 0; t < 4; ++t)
        afr[t] = *reinterpret_cast<const bf16x8*>(xs + (wrow + lr) * 136 + t * 32 + ks * 8);
    const unsigned short* wb =
        reinterpret_cast<const unsigned short*>(Waug) + lr * IN_C + ks * 8;

    for (int h = 0; h < HEADS; ++h) {
        const unsigned short* wh = wb + h * 32 * IN_C;
        f32x4 acc0 = {0.f, 0.f, 0.f, 0.f}, acc1 = {0.f, 0.f, 0.f, 0.f};
#pragma unroll
        for (int t = 0; t < 4; ++t) {
            bf16x8 b0 = *reinterpret_cast<const bf16x8*>(wh + t * 32);
            bf16x8 b1 = *reinterpret_cast<const bf16x8*>(wh + 16 * IN_C + t * 32);
            acc0 = __builtin_amdgcn_mfma_f32_16x16x32_bf16(afr[t], b0, acc0, 0, 0, 0);
            acc1 = __builtin_amdgcn_mfma_f32_16x16x32_bf16(afr[t], b1, acc1, 0, 0, 0);
        }
        // D layout: col = lane&15, row = (lane>>4)*4 + reg
#pragma unroll
        for (int r = 0; r < 4; ++r) {
            int grow = row0 + wrow + ks * 4 + r;
            if (grow < N) {
                h2out[(size_t)grow * HC + h * 32 + lr] = __float2bfloat16(acc0[r]);
                h2out[(size_t)grow * HC + h * 32 + 16 + lr] = __float2bfloat16(acc1[r]);
            }
        }
    }
    // augmented columns: a_src (cols 384..395) and a_dst (cols 400..411)
    {
        const unsigned short* wh = wb + HC * IN_C;
        f32x4 aa0 = {0.f, 0.f, 0.f, 0.f}, aa1 = {0.f, 0.f, 0.f, 0.f};
#pragma unroll
        for (int t = 0; t < 4; ++t) {
            bf16x8 b0 = *reinterpret_cast<const bf16x8*>(wh + t * 32);
            bf16x8 b1 = *reinterpret_cast<const bf16x8*>(wh + 16 * IN_C + t * 32);
            aa0 = __builtin_amdgcn_mfma_f32_16x16x32_bf16(afr[t], b0, aa0, 0, 0, 0);
            aa1 = __builtin_amdgcn_mfma_f32_16x16x32_bf16(afr[t], b1, aa1, 0, 0, 0);
        }
        if (lr < HEADS) {
#pragma unroll
            for (int r = 0; r < 4; ++r) {
                int grow = row0 + wrow + ks * 4 + r;
                if (grow < N) {
                    a_src[grow * HEADS + lr] = aa0[r];  // LOG2E pre-folded in Waug
                    a_dst[grow * HEADS + lr] = aa1[r];
                }
            }
        }
    }
}

// ---------------- aggregation: one wave per dst, 4-edge unroll, exp2 ----------------
// Pinned by gather-path bandwidth (653 MB random row-gathers ~6.3 TB/s effective).
__global__ __launch_bounds__(256) void k_aggregate(
    const int* __restrict__ cursor, const int* __restrict__ csr_src,
    const unsigned int* __restrict__ h2u, const float* __restrict__ a_src,
    const float* __restrict__ a_dst, const float* __restrict__ bias,
    float* __restrict__ y, int N) {
    const int d = (blockIdx.x * 256 + threadIdx.x) >> 6;  // wave id = dst node
    if (d >= N) return;
    const int l = threadIdx.x & 63;
    const int h0 = l >> 4;
    const float adv0 = a_dst[d * HEADS + h0];
    const float adv1 = a_dst[d * HEADS + h0 + 4];
    const float adv2 = a_dst[d * HEADS + h0 + 8];
    float ax0 = 0.f, ay0 = 0.f, ax1 = 0.f, ay1 = 0.f, ax2 = 0.f, ay2 = 0.f;
    float den0 = 0.f, den1 = 0.f, den2 = 0.f;
    const int m = min(cursor[d], BK);
    const int* bucket = csr_src + d * BK;
    int j = 0;
    for (; j + 4 <= m; j += 4) {
        int4 ss = *reinterpret_cast<const int4*>(bucket + j);
        int sa[4] = {ss.x, ss.y, ss.z, ss.w};
#pragma unroll
        for (int q = 0; q < 4; ++q) {
            const float* ap = a_src + sa[q] * HEADS;
            unsigned r = (unsigned)sa[q] * 192u;
            unsigned g0 = h2u[r + l], g1 = h2u[r + l + 64], g2 = h2u[r + l + 128];
            float v0 = ap[h0] + adv0;
            float v1 = ap[h0 + 4] + adv1;
            float v2 = ap[h0 + 8] + adv2;
            v0 = fmaxf(v0, NEG_SLOPE * v0);
            v1 = fmaxf(v1, NEG_SLOPE * v1);
            v2 = fmaxf(v2, NEG_SLOPE * v2);
            float w0 = exp2f(v0), w1 = exp2f(v1), w2 = exp2f(v2);
            ax0 = fmaf(w0, bflo(g0), ax0); ay0 = fmaf(w0, bfhi(g0), ay0); den0 += w0;
            ax1 = fmaf(w1, bflo(g1), ax1); ay1 = fmaf(w1, bfhi(g1), ay1); den1 += w1;
            ax2 = fmaf(w2, bflo(g2), ax2); ay2 = fmaf(w2, bfhi(g2), ay2); den2 += w2;
        }
    }
    for (; j < m; ++j) {
        int s = bucket[j];
        const float* ap = a_src + s * HEADS;
        unsigned r = (unsigned)s * 192u;
        unsigned g0 = h2u[r + l], g1 = h2u[r + l + 64], g2 = h2u[r + l + 128];
        float v0 = ap[h0] + adv0;
        float v1 = ap[h0 + 4] + adv1;
        float v2 = ap[h0 + 8] + adv2;
        v0 = fmaxf(v0, NEG_SLOPE * v0);
        v1 = fmaxf(v1, NEG_SLOPE * v1);
        v2 = fmaxf(v2, NEG_SLOPE * v2);
        float w0 = exp2f(v0), w1 = exp2f(v1), w2 = exp2f(v2);
        ax0 = fmaf(w0, bflo(g0), ax0); ay0 = fmaf(w0, bfhi(g0), ay0); den0 += w0;
        ax1 = fmaf(w1, bflo(g1), ax1); ay1 = fmaf(w1, bfhi(g1), ay1); den1 += w1;
        ax2 = fmaf(w2, bflo(g2), ax2); ay2 = fmaf(w2, bfhi(g2), ay2); den2 += w2;
    }
    {  // self-loop (s == d)
        const float* ap = a_src + d * HEADS;
        unsigned r = (unsigned)d * 192u;
        unsigned g0 = h2u[r + l], g1 = h2u[r + l + 64], g2 = h2u[r + l + 128];
        float v0 = ap[h0] + adv0;
        float v1 = ap[h0 + 4] + adv1;
        float v2 = ap[h0 + 8] + adv2;
        v0 = fmaxf(v0, NEG_SLOPE * v0);
        v1 = fmaxf(v1, NEG_SLOPE * v1);
        v2 = fmaxf(v2, NEG_SLOPE * v2);
        float w0 = exp2f(v0), w1 = exp2f(v1), w2 = exp2f(v2);
        ax0 = fmaf(w0, bflo(g0), ax0); ay0 = fmaf(w0, bfhi(g0), ay0); den0 += w0;
        ax1 = fmaf(w1, bflo(g1), ax1); ay1 = fmaf(w1, bfhi(g1), ay1); den1 += w1;
        ax2 = fmaf(w2, bflo(g2), ax2); ay2 = fmaf(w2, bfhi(g2), ay2); den2 += w2;
    }
    float tx = ax0 / (den0 + 1e-16f) + ax1 / (den1 + 1e-16f) + ax2 / (den2 + 1e-16f);
    float ty = ay0 / (den0 + 1e-16f) + ay1 / (den1 + 1e-16f) + ay2 / (den2 + 1e-16f);
    tx += __shfl_xor(tx, 16); ty += __shfl_xor(ty, 16);
    tx += __shfl_xor(tx, 32); ty += __shfl_xor(ty, 32);
    if (l < 16) {
        float2 b = *reinterpret_cast<const float2*>(bias + 2 * l);
        float2 o;
        o.x = fmaxf(tx * (1.f / HEADS) + b.x, 0.f);
        o.y = fmaxf(ty * (1.f / HEADS) + b.y, 0.f);
        *reinterpret_cast<float2*>(y + (size_t)d * OUT_C + 2 * l) = o;
    }
}

// ---------------- MLP epilogue ----------------
__global__ __launch_bounds__(256) void k_mlp(const float* __restrict__ y_in,
                                             const float* __restrict__ W1,
                                             const float* __restrict__ b1,
                                             const float* __restrict__ W2,
                                             const float* __restrict__ b2,
                                             float* __restrict__ out, int N) {
    __shared__ float sW1[OUT_C * 64];
    __shared__ float sW2[64 * OUT_C];
    __shared__ float sb1[64];
    __shared__ float sb2[OUT_C];
    const int tid = threadIdx.x;
    for (int i = tid; i < OUT_C * 64; i += 256) { sW1[i] = W1[i]; sW2[i] = W2[i]; }
    if (tid < 64) sb1[tid] = b1[tid];
    if (tid < OUT_C) sb2[tid] = b2[tid];
    __syncthreads();
    const int n = blockIdx.x * 256 + tid;
    if (n >= N) return;
    float y[OUT_C];
#pragma unroll
    for (int c = 0; c < OUT_C / 4; ++c) {
        float4 v = *reinterpret_cast<const float4*>(y_in + (size_t)n * OUT_C + 4 * c);
        y[4 * c + 0] = v.x; y[4 * c + 1] = v.y; y[4 * c + 2] = v.z; y[4 * c + 3] = v.w;
    }
    float z2[OUT_C];
#pragma unroll
    for (int c = 0; c < OUT_C; ++c) z2[c] = sb2[c];
    for (int j = 0; j < 64; ++j) {
        float t = sb1[j];
#pragma unroll
        for (int c = 0; c < OUT_C; ++c) t = fmaf(y[c], sW1[c * 64 + j], t);
        t = t > 0.f ? t : 0.f;
#pragma unroll
        for (int c = 0; c < OUT_C; ++c) z2[c] = fmaf(t, sW2[j * OUT_C + c], z2[c]);
    }
#pragma unroll
    for (int c = 0; c < OUT_C; ++c) {
        float r = y[c] + z2[c];
        r = r > 0.f ? r : 0.f;
        out[(size_t)n * OUT_C + c] = r;
    }
}

extern "C" void kernel_launch(void* const* d_in, const int* in_sizes, int n_in,
                              void* d_out, int out_size, void* d_ws, size_t ws_size,
                              hipStream_t stream) {
    const float* x = (const float*)d_in[0];
    const int* ei = (const int*)d_in[1];  // int32 planar [2,E]
    const float* W = (const float*)d_in[2];
    const float* att_src = (const float*)d_in[3];
    const float* att_dst = (const float*)d_in[4];
    const float* bias = (const float*)d_in[5];
    const float* W1 = (const float*)d_in[6];
    const float* b1 = (const float*)d_in[7];
    const float* W2 = (const float*)d_in[8];
    const float* b2 = (const float*)d_in[9];
    const int N = in_sizes[0] / IN_C;
    const int E = in_sizes[1] / 2;

    // workspace: h2[N*384]bf16 | a_src[N*12]f32 | a_dst[N*12] | y[N*32] |
    //            cursor[N]i32 | csr_src[N*BK]i32 | Waug[416*128]bf16
    char* ws = (char*)d_ws;
    __hip_bfloat16* h2 = (__hip_bfloat16*)ws;
    float* a_src = (float*)(ws + (size_t)N * HC * 2);
    float* a_dst = a_src + (size_t)N * HEADS;
    float* y = a_dst + (size_t)N * HEADS;
    int* cursor = (int*)(y + (size_t)N * OUT_C);
    int* csr_src = cursor + N;
    __hip_bfloat16* Waug = (__hip_bfloat16*)(csr_src + (size_t)N * BK);

    int prep_blocks = (AUGC * IN_C + N + 255) / 256;
    k_prep<<<prep_blocks, 256, 0, stream>>>(W, att_src, att_dst, Waug, cursor, N);

    int GB = (N + 63) / 64;
    int SB = (E + 255) / 256;
    k_gemm_scatter<<<GB + SB, 256, 0, stream>>>(x, Waug, h2, a_src, a_dst,
                                                ei, cursor, csr_src, N, E, GB);

    int agg_blocks = (N * 64 + 255) / 256;  // one wave per dst
    k_aggregate<<<agg_blocks, 256, 0, stream>>>(cursor, csr_src,
                                                (const unsigned int*)h2, a_src, a_dst,
                                                bias, y, N);
    k_mlp<<<(N + 255) / 256, 256, 0, stream>>>(y, W1, b1, W2, b2, (float*)d_out, N);
}

// Round 19
// 228.649 us; speedup vs baseline: 1.0173x; 1.0076x over previous
//
#include <hip/hip_runtime.h>
#include <hip/hip_bf16.h>

#define IN_C 128
#define HEADS 12
#define OUT_C 32
#define HC 384   // HEADS*OUT_C
#define BK 96    // bucket capacity per dst (P(deg>=96), lambda=16: ~1e-48)
#define NEG_SLOPE 0.2f
#define LOG2E 1.44269504f
#define AUGC 416  // 384 h-cols + 16 (12 Wa + pad) + 16 (12 Wd + pad)

typedef __attribute__((ext_vector_type(8))) short bf16x8;
typedef __attribute__((ext_vector_type(4))) float f32x4;

static __device__ __forceinline__ unsigned short bfbits(float f) {
    __hip_bfloat16 b = __float2bfloat16(f);
    return *reinterpret_cast<unsigned short*>(&b);
}
static __device__ __forceinline__ float bflo(unsigned int g) {
    return __uint_as_float(g << 16);
}
static __device__ __forceinline__ float bfhi(unsigned int g) {
    return __uint_as_float(g & 0xffff0000u);
}

// ---------------- kernel 0: prep ----------------
// Waug[col][k] bf16: cols 0..383 = W^T; cols 384+h = LOG2E*(W_h @ att_src_h);
// cols 400+h = LOG2E*(W_h @ att_dst_h). Also zeroes cursor.
__global__ void k_prep(const float* __restrict__ W, const float* __restrict__ att_src,
                       const float* __restrict__ att_dst,
                       __hip_bfloat16* __restrict__ Waug, int* __restrict__ cursor,
                       int N) {
    int i = blockIdx.x * 256 + threadIdx.x;
    if (i < HC * IN_C) {
        int col = i >> 7, k = i & 127;
        Waug[(size_t)col * IN_C + k] = __float2bfloat16(W[k * HC + col]);
    } else if (i < AUGC * IN_C) {
        int j = i - HC * IN_C;
        int idx = j >> 7;  // 0..31 (aug col index)
        int k = j & 127;
        float v = 0.f;
        if (idx < HEADS) {
            for (int c = 0; c < 32; ++c) v += W[k * HC + idx * 32 + c] * att_src[idx * 32 + c];
            v *= LOG2E;
        } else if (idx >= 16 && idx < 16 + HEADS) {
            int h = idx - 16;
            for (int c = 0; c < 32; ++c) v += W[k * HC + h * 32 + c] * att_dst[h * 32 + c];
            v *= LOG2E;
        }
        Waug[(size_t)(HC + idx) * IN_C + k] = __float2bfloat16(v);
    } else if (i - AUGC * IN_C < N) {
        cursor[i - AUGC * IN_C] = 0;
    }
}

// ---------------- kernel 1 (fused): MFMA gemm (h2 + a_src/a_dst)  |  edge scatter ----------------
__global__ __launch_bounds__(256) void k_gemm_scatter(
    const float* __restrict__ x, const __hip_bfloat16* __restrict__ Waug,
    __hip_bfloat16* __restrict__ h2out, float* __restrict__ a_src,
    float* __restrict__ a_dst, const int* __restrict__ ei,
    int* __restrict__ cursor, int* __restrict__ csr_src,
    int N, int E, int GB) {
    if (blockIdx.x >= GB) {  // ---- scatter part: 2 edges per thread ----
        int e0 = ((blockIdx.x - GB) * 256 + threadIdx.x) * 2;
        if (e0 + 1 < E) {
            int2 s2 = *reinterpret_cast<const int2*>(ei + e0);
            int2 d2 = *reinterpret_cast<const int2*>(ei + E + e0);
            int p0 = atomicAdd(&cursor[d2.x], 1);
            if (p0 < BK) csr_src[d2.x * BK + p0] = s2.x;
            int p1 = atomicAdd(&cursor[d2.y], 1);
            if (p1 < BK) csr_src[d2.y * BK + p1] = s2.y;
        } else if (e0 < E) {
            int s = ei[e0], d = ei[E + e0];
            int pos = atomicAdd(&cursor[d], 1);
            if (pos < BK) csr_src[d * BK + pos] = s;
        }
        return;
    }
    // ---- gemm part ----
    __shared__ unsigned short xs[64 * 136];
    const int tid = threadIdx.x;
    const int row0 = blockIdx.x * 64;
    for (int i = tid * 4; i < 64 * IN_C; i += 1024) {
        int r = i >> 7, k = i & 127;
        float4 v = make_float4(0.f, 0.f, 0.f, 0.f);
        if (row0 + r < N) v = *reinterpret_cast<const float4*>(x + (size_t)(row0 + r) * IN_C + k);
        unsigned short* dst = xs + r * 136 + k;
        dst[0] = bfbits(v.x); dst[1] = bfbits(v.y); dst[2] = bfbits(v.z); dst[3] = bfbits(v.w);
    }
    __syncthreads();
    const int l = tid & 63;
    const int wrow = (tid >> 6) * 16;
    const int lr = l & 15;
    const int ks = l >> 4;
    bf16x8 afr[4];
#pragma unroll
    for (int t = 0; t < 4; ++t)
        afr[t] = *reinterpret_cast<const bf16x8*>(xs + (wrow + lr) * 136 + t * 32 + ks * 8);
    const unsigned short* wb =
        reinterpret_cast<const unsigned short*>(Waug) + lr * IN_C + ks * 8;

    for (int h = 0; h < HEADS; ++h) {
        const unsigned short* wh = wb + h * 32 * IN_C;
        f32x4 acc0 = {0.f, 0.f, 0.f, 0.f}, acc1 = {0.f, 0.f, 0.f, 0.f};
#pragma unroll
        for (int t = 0; t < 4; ++t) {
            bf16x8 b0 = *reinterpret_cast<const bf16x8*>(wh + t * 32);
            bf16x8 b1 = *reinterpret_cast<const bf16x8*>(wh + 16 * IN_C + t * 32);
            acc0 = __builtin_amdgcn_mfma_f32_16x16x32_bf16(afr[t], b0, acc0, 0, 0, 0);
            acc1 = __builtin_amdgcn_mfma_f32_16x16x32_bf16(afr[t], b1, acc1, 0, 0, 0);
        }
#pragma unroll
        for (int r = 0; r < 4; ++r) {
            int grow = row0 + wrow + ks * 4 + r;
            if (grow < N) {
                h2out[(size_t)grow * HC + h * 32 + lr] = __float2bfloat16(acc0[r]);
                h2out[(size_t)grow * HC + h * 32 + 16 + lr] = __float2bfloat16(acc1[r]);
            }
        }
    }
    {   // augmented columns -> a_src, a_dst (LOG2E pre-folded)
        const unsigned short* wh = wb + HC * IN_C;
        f32x4 aa0 = {0.f, 0.f, 0.f, 0.f}, aa1 = {0.f, 0.f, 0.f, 0.f};
#pragma unroll
        for (int t = 0; t < 4; ++t) {
            bf16x8 b0 = *reinterpret_cast<const bf16x8*>(wh + t * 32);
            bf16x8 b1 = *reinterpret_cast<const bf16x8*>(wh + 16 * IN_C + t * 32);
            aa0 = __builtin_amdgcn_mfma_f32_16x16x32_bf16(afr[t], b0, aa0, 0, 0, 0);
            aa1 = __builtin_amdgcn_mfma_f32_16x16x32_bf16(afr[t], b1, aa1, 0, 0, 0);
        }
        if (lr < HEADS) {
#pragma unroll
            for (int r = 0; r < 4; ++r) {
                int grow = row0 + wrow + ks * 4 + r;
                if (grow < N) {
                    a_src[grow * HEADS + lr] = aa0[r];
                    a_dst[grow * HEADS + lr] = aa1[r];
                }
            }
        }
    }
}

// ---------------- aggregation: one wave per dst, 2 payload requests/edge ----------------
// lane l: b64 @ uint 2l  -> head hA=l>>3, flat channels 4l..4l+3 (local 4(l&7)..+3)
//         b32 @ uint 128+l -> head hB=8+(l>>4), local channels 2(l&15),+1
// Tail: per-head normalize, xor-shfl head-sums (A:8/16/32, B:16/32), wave LDS combine.
__global__ __launch_bounds__(256) void k_aggregate(
    const int* __restrict__ cursor, const int* __restrict__ csr_src,
    const unsigned int* __restrict__ h2u, const float* __restrict__ a_src,
    const float* __restrict__ a_dst, const float* __restrict__ bias,
    float* __restrict__ y, int N) {
    __shared__ float ylds[4][32];
    const int d = (blockIdx.x * 256 + threadIdx.x) >> 6;
    if (d >= N) return;
    const int wv = threadIdx.x >> 6;
    const int l = threadIdx.x & 63;
    const int hA = l >> 3;
    const int hB = 8 + (l >> 4);
    const float advA = a_dst[d * HEADS + hA];
    const float advB = a_dst[d * HEADS + hB];
    float aA0 = 0.f, aA1 = 0.f, aA2 = 0.f, aA3 = 0.f, denA = 0.f;
    float aB0 = 0.f, aB1 = 0.f, denB = 0.f;
    const int m = min(cursor[d], BK);
    const int* bucket = csr_src + d * BK;

    auto body = [&](int s) {
        const float* ap = a_src + s * HEADS;
        size_t r = (size_t)s * 192u;
        uint2 gA = *reinterpret_cast<const uint2*>(h2u + r + 2 * l);
        unsigned gB = h2u[r + 128 + l];
        float vA = ap[hA] + advA;
        float vB = ap[hB] + advB;
        vA = fmaxf(vA, NEG_SLOPE * vA);
        vB = fmaxf(vB, NEG_SLOPE * vB);
        float wA = exp2f(vA), wB = exp2f(vB);
        aA0 = fmaf(wA, bflo(gA.x), aA0);
        aA1 = fmaf(wA, bfhi(gA.x), aA1);
        aA2 = fmaf(wA, bflo(gA.y), aA2);
        aA3 = fmaf(wA, bfhi(gA.y), aA3);
        denA += wA;
        aB0 = fmaf(wB, bflo(gB), aB0);
        aB1 = fmaf(wB, bfhi(gB), aB1);
        denB += wB;
    };
    int j = 0;
    for (; j + 4 <= m; j += 4) {
        int4 ss = *reinterpret_cast<const int4*>(bucket + j);
        body(ss.x); body(ss.y); body(ss.z); body(ss.w);
    }
    for (; j < m; ++j) body(bucket[j]);
    body(d);  // self-loop

    // per-head softmax normalize
    float rA = 1.f / (denA + 1e-16f), rB = 1.f / (denB + 1e-16f);
    aA0 *= rA; aA1 *= rA; aA2 *= rA; aA3 *= rA;
    aB0 *= rB; aB1 *= rB;
    // sum over heads: A across lanes strided 8; B strided 16
#pragma unroll
    for (int off = 8; off <= 32; off <<= 1) {
        aA0 += __shfl_xor(aA0, off);
        aA1 += __shfl_xor(aA1, off);
        aA2 += __shfl_xor(aA2, off);
        aA3 += __shfl_xor(aA3, off);
    }
#pragma unroll
    for (int off = 16; off <= 32; off <<= 1) {
        aB0 += __shfl_xor(aB0, off);
        aB1 += __shfl_xor(aB1, off);
    }
    if (l < 8) {
        ylds[wv][4 * l + 0] = aA0;
        ylds[wv][4 * l + 1] = aA1;
        ylds[wv][4 * l + 2] = aA2;
        ylds[wv][4 * l + 3] = aA3;
    }
    // same-wave DS in-order: writes above complete before reads below
    if (l < 16) {
        float2 b = *reinterpret_cast<const float2*>(bias + 2 * l);
        float2 o;
        o.x = fmaxf((ylds[wv][2 * l] + aB0) * (1.f / HEADS) + b.x, 0.f);
        o.y = fmaxf((ylds[wv][2 * l + 1] + aB1) * (1.f / HEADS) + b.y, 0.f);
        *reinterpret_cast<float2*>(y + (size_t)d * OUT_C + 2 * l) = o;
    }
}

// ---------------- MLP epilogue (b128 LDS reads, W1 transposed) ----------------
__global__ __launch_bounds__(256) void k_mlp(const float* __restrict__ y_in,
                                             const float* __restrict__ W1,
                                             const float* __restrict__ b1,
                                             const float* __restrict__ W2,
                                             const float* __restrict__ b2,
                                             float* __restrict__ out, int N) {
    __shared__ float sW1t[64 * 32];  // [j][c]
    __shared__ float sW2[64 * OUT_C];  // [j][c]
    __shared__ float sb1[64];
    __shared__ float sb2[OUT_C];
    const int tid = threadIdx.x;
    for (int i = tid; i < OUT_C * 64; i += 256) {
        int c = i >> 6, j = i & 63;
        sW1t[j * 32 + c] = W1[c * 64 + j];
        sW2[i] = W2[i];
    }
    if (tid < 64) sb1[tid] = b1[tid];
    if (tid < OUT_C) sb2[tid] = b2[tid];
    __syncthreads();
    const int n = blockIdx.x * 256 + tid;
    if (n >= N) return;
    float y[OUT_C];
#pragma unroll
    for (int c = 0; c < OUT_C / 4; ++c) {
        float4 v = *reinterpret_cast<const float4*>(y_in + (size_t)n * OUT_C + 4 * c);
        y[4 * c + 0] = v.x; y[4 * c + 1] = v.y; y[4 * c + 2] = v.z; y[4 * c + 3] = v.w;
    }
    float z2[OUT_C];
#pragma unroll
    for (int c = 0; c < OUT_C; ++c) z2[c] = sb2[c];
    for (int j = 0; j < 64; ++j) {
        float t = sb1[j];
#pragma unroll
        for (int c4 = 0; c4 < 8; ++c4) {
            float4 w = *reinterpret_cast<const float4*>(sW1t + j * 32 + 4 * c4);
            t = fmaf(y[4 * c4 + 0], w.x, t);
            t = fmaf(y[4 * c4 + 1], w.y, t);
            t = fmaf(y[4 * c4 + 2], w.z, t);
            t = fmaf(y[4 * c4 + 3], w.w, t);
        }
        t = t > 0.f ? t : 0.f;
#pragma unroll
        for (int c4 = 0; c4 < 8; ++c4) {
            float4 w = *reinterpret_cast<const float4*>(sW2 + j * 32 + 4 * c4);
            z2[4 * c4 + 0] = fmaf(t, w.x, z2[4 * c4 + 0]);
            z2[4 * c4 + 1] = fmaf(t, w.y, z2[4 * c4 + 1]);
            z2[4 * c4 + 2] = fmaf(t, w.z, z2[4 * c4 + 2]);
            z2[4 * c4 + 3] = fmaf(t, w.w, z2[4 * c4 + 3]);
        }
    }
#pragma unroll
    for (int c = 0; c < OUT_C; ++c) {
        float r = y[c] + z2[c];
        r = r > 0.f ? r : 0.f;
        out[(size_t)n * OUT_C + c] = r;
    }
}

extern "C" void kernel_launch(void* const* d_in, const int* in_sizes, int n_in,
                              void* d_out, int out_size, void* d_ws, size_t ws_size,
                              hipStream_t stream) {
    const float* x = (const float*)d_in[0];
    const int* ei = (const int*)d_in[1];  // int32 planar [2,E]
    const float* W = (const float*)d_in[2];
    const float* att_src = (const float*)d_in[3];
    const float* att_dst = (const float*)d_in[4];
    const float* bias = (const float*)d_in[5];
    const float* W1 = (const float*)d_in[6];
    const float* b1 = (const float*)d_in[7];
    const float* W2 = (const float*)d_in[8];
    const float* b2 = (const float*)d_in[9];
    const int N = in_sizes[0] / IN_C;
    const int E = in_sizes[1] / 2;

    // workspace: h2[N*384]bf16 | a_src[N*12]f32 | a_dst[N*12] | y[N*32] |
    //            cursor[N]i32 | csr_src[N*BK]i32 | Waug[416*128]bf16
    char* ws = (char*)d_ws;
    __hip_bfloat16* h2 = (__hip_bfloat16*)ws;
    float* a_src = (float*)(ws + (size_t)N * HC * 2);
    float* a_dst = a_src + (size_t)N * HEADS;
    float* y = a_dst + (size_t)N * HEADS;
    int* cursor = (int*)(y + (size_t)N * OUT_C);
    int* csr_src = cursor + N;
    __hip_bfloat16* Waug = (__hip_bfloat16*)(csr_src + (size_t)N * BK);

    int prep_blocks = (AUGC * IN_C + N + 255) / 256;
    k_prep<<<prep_blocks, 256, 0, stream>>>(W, att_src, att_dst, Waug, cursor, N);

    int GB = (N + 63) / 64;
    int SB = ((E + 1) / 2 + 255) / 256;
    k_gemm_scatter<<<GB + SB, 256, 0, stream>>>(x, Waug, h2, a_src, a_dst,
                                                ei, cursor, csr_src, N, E, GB);

    int agg_blocks = (N * 64 + 255) / 256;  // one wave per dst
    k_aggregate<<<agg_blocks, 256, 0, stream>>>(cursor, csr_src,
                                                (const unsigned int*)h2, a_src, a_dst,
                                                bias, y, N);
    k_mlp<<<(N + 255) / 256, 256, 0, stream>>>(y, W1, b1, W2, b2, (float*)d_out, N);
}